// Round 1
// baseline (379.646 us; speedup 1.0000x reference)
//
#include <hip/hip_runtime.h>
#include <math.h>

#define NN 500000   // nodes
#define NB 4096     // segments
#define DD 256      // feature dim

__device__ __forceinline__ float gelu_exact(float v) {
    return 0.5f * v * (1.0f + erff(v * 0.70710678118654752440f));
}

// ---------------------------------------------------------------------------
// Kernel 1: one block per segment. Streams the segment's rows once.
// Computes: center=segsum(gelu), neighbor=segmax(gelu), sum_out, max_out,
// and attention branch via online softmax (wave w == head w).
// Writes att/max/sum into their slices of merged(B,4D); center/neighbor to ws.
// ---------------------------------------------------------------------------
__global__ __launch_bounds__(256) void seg_kernel(
    const float* __restrict__ x,
    const int*   __restrict__ seg,
    const float* __restrict__ att_w,
    float* __restrict__ merged,    // (NB, 1024)
    float* __restrict__ center,    // (NB, 256)
    float* __restrict__ neighbor)  // (NB, 256)
{
    const int b = blockIdx.x;
    const int d = threadIdx.x;

    // lower_bound(seg, b) and lower_bound(seg, b+1) — wave-uniform binary search
    int lo = 0, hi = NN;
    while (lo < hi) { int mid = (lo + hi) >> 1; if (seg[mid] < b) lo = mid + 1; else hi = mid; }
    const int start = lo;
    hi = NN;
    while (lo < hi) { int mid = (lo + hi) >> 1; if (seg[mid] <= b) lo = mid + 1; else hi = mid; }
    const int end = lo;

    const float aw = att_w[d];   // att_w flat: [h][k], d = h*64+k

    float c_sum = 0.f;
    float n_max = -INFINITY;
    float s_sum = 0.f;
    float m_max = -INFINITY;
    float acc   = 0.f;          // online-softmax weighted accumulator (this column)
    float sm_m  = -INFINITY;    // running max (wave-uniform per head)
    float sm_l  = 0.f;          // running denom

    for (int i = start; i < end; ++i) {
        float v = x[(size_t)i * DD + d];

        float h = gelu_exact(v);
        c_sum += h;
        n_max  = fmaxf(n_max, h);
        s_sum += v;
        m_max  = fmaxf(m_max, v);

        // per-head dot: reduce v*aw over the 64 lanes of this wave (= head)
        float t = v * aw;
        #pragma unroll
        for (int off = 32; off; off >>= 1) t += __shfl_xor(t, off, 64);
        float alpha = (t >= 0.f) ? t : 0.2f * t;   // leaky_relu slope 0.2

        // online softmax update
        float m_new   = fmaxf(sm_m, alpha);
        float fscale  = __expf(sm_m - m_new);      // exp(-inf)=0 handles first row
        float e       = __expf(alpha - m_new);
        sm_l = sm_l * fscale + e;
        acc  = acc  * fscale + e * v;
        sm_m = m_new;
    }

    float att = (sm_l > 0.f) ? (acc / sm_l) : 0.f;

    float* mrow = merged + (size_t)b * 1024;
    mrow[256 + d] = att;     // att_out slice
    mrow[512 + d] = m_max;   // max_out slice
    mrow[768 + d] = s_sum;   // sum_out slice
    center  [(size_t)b * DD + d] = c_sum;
    neighbor[(size_t)b * DD + d] = n_max;
}

// ---------------------------------------------------------------------------
// Generic fp32 tiled GEMM: C[M x ldc] (cols n0..) = A[M x K] @ W[N x K]^T + bias
// 64x64 tile per 256-thread block, BK=32, 4x4 micro-tile per thread.
// Grid: (M/64, N/64). M, N multiples of 64; K multiple of 32.
// ---------------------------------------------------------------------------
__global__ __launch_bounds__(256) void gemm_abt(
    const float* __restrict__ A,
    const float* __restrict__ W,
    const float* __restrict__ bias,
    float* __restrict__ C,
    int K, int ldc)
{
    __shared__ __align__(16) float As[32][68];
    __shared__ __align__(16) float Ws[32][68];

    const int m0 = blockIdx.x * 64;
    const int n0 = blockIdx.y * 64;
    const int t  = threadIdx.x;
    const int tx = t & 15;        // output col group
    const int ty = t >> 4;        // output row group
    const int lr = t >> 3;        // load row 0..31 (and +32)
    const int lk = (t & 7) * 4;   // load k offset (float4)

    float acc[4][4] = {};

    for (int k0 = 0; k0 < K; k0 += 32) {
        float4 a0 = *reinterpret_cast<const float4*>(&A[(size_t)(m0 + lr)      * K + k0 + lk]);
        float4 a1 = *reinterpret_cast<const float4*>(&A[(size_t)(m0 + lr + 32) * K + k0 + lk]);
        float4 w0 = *reinterpret_cast<const float4*>(&W[(size_t)(n0 + lr)      * K + k0 + lk]);
        float4 w1 = *reinterpret_cast<const float4*>(&W[(size_t)(n0 + lr + 32) * K + k0 + lk]);

        __syncthreads();  // previous iteration's LDS reads complete
        As[lk+0][lr] = a0.x; As[lk+1][lr] = a0.y; As[lk+2][lr] = a0.z; As[lk+3][lr] = a0.w;
        As[lk+0][lr+32] = a1.x; As[lk+1][lr+32] = a1.y; As[lk+2][lr+32] = a1.z; As[lk+3][lr+32] = a1.w;
        Ws[lk+0][lr] = w0.x; Ws[lk+1][lr] = w0.y; Ws[lk+2][lr] = w0.z; Ws[lk+3][lr] = w0.w;
        Ws[lk+0][lr+32] = w1.x; Ws[lk+1][lr+32] = w1.y; Ws[lk+2][lr+32] = w1.z; Ws[lk+3][lr+32] = w1.w;
        __syncthreads();

        #pragma unroll
        for (int kk = 0; kk < 32; ++kk) {
            float4 av = *reinterpret_cast<const float4*>(&As[kk][ty * 4]);
            float4 wv = *reinterpret_cast<const float4*>(&Ws[kk][tx * 4]);
            float a4[4] = {av.x, av.y, av.z, av.w};
            float w4[4] = {wv.x, wv.y, wv.z, wv.w};
            #pragma unroll
            for (int i = 0; i < 4; ++i)
                #pragma unroll
                for (int j = 0; j < 4; ++j)
                    acc[i][j] = fmaf(a4[i], w4[j], acc[i][j]);
        }
    }

    #pragma unroll
    for (int i = 0; i < 4; ++i) {
        const size_t row = (size_t)(m0 + ty * 4 + i) * ldc + n0;
        #pragma unroll
        for (int j = 0; j < 4; ++j)
            C[row + tx * 4 + j] = acc[i][j] + bias[n0 + tx * 4 + j];
    }
}

// ---------------------------------------------------------------------------
// Kernel 3: GRU gate elementwise -> writes rnn_out slice of merged
// ---------------------------------------------------------------------------
__global__ __launch_bounds__(256) void gru_kernel(
    const float* __restrict__ gi,        // (NB, 768)
    const float* __restrict__ gh,        // (NB, 768)
    const float* __restrict__ neighbor,  // (NB, 256)
    float* __restrict__ merged)          // (NB, 1024)
{
    const int b = blockIdx.x;
    const int j = threadIdx.x;
    const float* gib = gi + (size_t)b * 768;
    const float* ghb = gh + (size_t)b * 768;

    float r  = 1.f / (1.f + __expf(-(gib[j]       + ghb[j])));
    float z  = 1.f / (1.f + __expf(-(gib[256 + j] + ghb[256 + j])));
    float ng = tanhf(gib[512 + j] + r * ghb[512 + j]);
    float nb = neighbor[(size_t)b * 256 + j];

    merged[(size_t)b * 1024 + j] = (1.f - z) * ng + z * nb;
}

// ---------------------------------------------------------------------------
extern "C" void kernel_launch(void* const* d_in, const int* in_sizes, int n_in,
                              void* d_out, int out_size, void* d_ws, size_t ws_size,
                              hipStream_t stream) {
    const float* x       = (const float*)d_in[0];
    const int*   seg     = (const int*)  d_in[1];
    const float* att_w   = (const float*)d_in[2];
    const float* w_ih    = (const float*)d_in[3];
    const float* w_hh    = (const float*)d_in[4];
    const float* b_ih    = (const float*)d_in[5];
    const float* b_hh    = (const float*)d_in[6];
    const float* merge_w = (const float*)d_in[7];
    const float* merge_b = (const float*)d_in[8];
    float* out = (float*)d_out;

    // workspace layout (floats):
    float* ws       = (float*)d_ws;
    float* merged   = ws;                              // 4096*1024 = 16 MB
    float* center   = merged   + (size_t)NB * 1024;    // 4096*256  =  4 MB
    float* neighbor = center   + (size_t)NB * DD;      // 4096*256  =  4 MB
    float* gi       = neighbor + (size_t)NB * DD;      // 4096*768  = 12 MB
    float* gh       = gi       + (size_t)NB * 768;     // 4096*768  = 12 MB
    // total 48 MB

    // 1) fused segment pass
    seg_kernel<<<NB, 256, 0, stream>>>(x, seg, att_w, merged, center, neighbor);

    // 2) gi = center @ w_ih^T + b_ih ; gh = neighbor @ w_hh^T + b_hh
    dim3 g1(NB / 64, 768 / 64);
    gemm_abt<<<g1, 256, 0, stream>>>(center,   w_ih, b_ih, gi, DD, 768);
    gemm_abt<<<g1, 256, 0, stream>>>(neighbor, w_hh, b_hh, gh, DD, 768);

    // 3) GRU gates -> rnn slice of merged
    gru_kernel<<<NB, 256, 0, stream>>>(gi, gh, neighbor, merged);

    // 4) out = merged @ merge_w^T + merge_b
    dim3 g2(NB / 64, DD / 64);
    gemm_abt<<<g2, 256, 0, stream>>>(merged, merge_w, merge_b, out, 1024, DD);
}

// Round 2
// 248.944 us; speedup vs baseline: 1.5250x; 1.5250x over previous
//
#include <hip/hip_runtime.h>
#include <math.h>

#define NN 500000   // nodes
#define NB 4096     // segments
#define DD 256      // feature dim

// Fast exact-enough gelu: Abramowitz-Stegun 7.1.26 erf (|err| <= 1.5e-7), branchless.
__device__ __forceinline__ float gelu_fast(float x) {
    float z  = fabsf(x) * 0.70710678118654752440f;
    float t  = __builtin_amdgcn_rcpf(fmaf(0.3275911f, z, 1.0f));
    float p  = fmaf(1.061405429f, t, -1.453152027f);
    p = fmaf(p, t, 1.421413741f);
    p = fmaf(p, t, -0.284496736f);
    p = fmaf(p, t, 0.254829592f);
    p = p * t;
    float ez = __expf(-z * z);          // v_exp_f32 path
    float erfv = copysignf(1.0f - p * ez, x);
    return 0.5f * x * (1.0f + erfv);
}

// ---------------------------------------------------------------------------
// Kernel 1: one block (4 waves) per segment. Wave w handles rows start+4k+w,
// one full row per wave: lane l holds columns 4l..4l+3 (float4).
// Head h = l>>4 (16 lanes per head). Plain-exp segment softmax (no max shift).
// Cross-wave combine at the end via LDS.
// ---------------------------------------------------------------------------
__global__ __launch_bounds__(256) void seg_kernel(
    const float* __restrict__ x,
    const int*   __restrict__ seg,
    const float* __restrict__ att_w,
    float* __restrict__ merged,    // (NB, 1024)
    float* __restrict__ center,    // (NB, 256)
    float* __restrict__ neighbor)  // (NB, 256)
{
    const int b   = blockIdx.x;
    const int tid = threadIdx.x;
    const int w   = tid >> 6;     // wave 0..3
    const int l   = tid & 63;     // lane

    // wave-uniform binary search: [start, end) rows of segment b
    int lo = 0, hi = NN;
    while (lo < hi) { int mid = (lo + hi) >> 1; if (seg[mid] < b) lo = mid + 1; else hi = mid; }
    const int start = lo;
    hi = NN;
    while (lo < hi) { int mid = (lo + hi) >> 1; if (seg[mid] <= b) lo = mid + 1; else hi = mid; }
    const int end = lo;

    const float4 aw = *reinterpret_cast<const float4*>(&att_w[4 * l]);

    float c0 = 0.f, c1 = 0.f, c2 = 0.f, c3 = 0.f;           // segsum(gelu)
    float n0 = -INFINITY, n1 = -INFINITY, n2 = -INFINITY, n3 = -INFINITY; // segmax(gelu)
    float s0 = 0.f, s1 = 0.f, s2 = 0.f, s3 = 0.f;           // segsum(x)
    float m0 = -INFINITY, m1 = -INFINITY, m2 = -INFINITY, m3 = -INFINITY; // segmax(x)
    float a0 = 0.f, a1 = 0.f, a2 = 0.f, a3 = 0.f;           // sum e*x
    float lsum = 0.f;                                        // sum e (per head)

    int i = start + w;
    float4 v;
    if (i < end) v = *reinterpret_cast<const float4*>(&x[(size_t)i * DD + 4 * l]);
    while (i < end) {
        const int inext = i + 4;
        float4 vn;
        if (inext < end) vn = *reinterpret_cast<const float4*>(&x[(size_t)inext * DD + 4 * l]);

        float g0 = gelu_fast(v.x), g1 = gelu_fast(v.y), g2 = gelu_fast(v.z), g3 = gelu_fast(v.w);
        c0 += g0; c1 += g1; c2 += g2; c3 += g3;
        n0 = fmaxf(n0, g0); n1 = fmaxf(n1, g1); n2 = fmaxf(n2, g2); n3 = fmaxf(n3, g3);
        s0 += v.x; s1 += v.y; s2 += v.z; s3 += v.w;
        m0 = fmaxf(m0, v.x); m1 = fmaxf(m1, v.y); m2 = fmaxf(m2, v.z); m3 = fmaxf(m3, v.w);

        // head dot: partial over this lane's 4 cols, reduce over the 16-lane head group
        float t = fmaf(v.x, aw.x, fmaf(v.y, aw.y, fmaf(v.z, aw.z, v.w * aw.w)));
        t += __shfl_xor(t, 1, 64);
        t += __shfl_xor(t, 2, 64);
        t += __shfl_xor(t, 4, 64);
        t += __shfl_xor(t, 8, 64);
        float alpha = (t >= 0.f) ? t : 0.2f * t;   // leaky_relu 0.2
        float e = __expf(alpha);                    // no max-shift: |alpha| small
        lsum += e;
        a0 = fmaf(e, v.x, a0); a1 = fmaf(e, v.y, a1); a2 = fmaf(e, v.z, a2); a3 = fmaf(e, v.w, a3);

        v = vn; i = inext;
    }

    // ---- cross-wave combine ----
    __shared__ float lds[5][4][256];   // c, n, s, m, a  (20 KB)
    __shared__ float ldsl[4][4];       // per-wave per-head denom partials
    const int c = 4 * l;
    lds[0][w][c+0] = c0; lds[0][w][c+1] = c1; lds[0][w][c+2] = c2; lds[0][w][c+3] = c3;
    lds[1][w][c+0] = n0; lds[1][w][c+1] = n1; lds[1][w][c+2] = n2; lds[1][w][c+3] = n3;
    lds[2][w][c+0] = s0; lds[2][w][c+1] = s1; lds[2][w][c+2] = s2; lds[2][w][c+3] = s3;
    lds[3][w][c+0] = m0; lds[3][w][c+1] = m1; lds[3][w][c+2] = m2; lds[3][w][c+3] = m3;
    lds[4][w][c+0] = a0; lds[4][w][c+1] = a1; lds[4][w][c+2] = a2; lds[4][w][c+3] = a3;
    if ((l & 15) == 0) ldsl[w][l >> 4] = lsum;
    __syncthreads();

    // thread tid owns output column tid
    const int d = tid;
    float cs = lds[0][0][d] + lds[0][1][d] + lds[0][2][d] + lds[0][3][d];
    float nm = fmaxf(fmaxf(lds[1][0][d], lds[1][1][d]), fmaxf(lds[1][2][d], lds[1][3][d]));
    float ss = lds[2][0][d] + lds[2][1][d] + lds[2][2][d] + lds[2][3][d];
    float mm = fmaxf(fmaxf(lds[3][0][d], lds[3][1][d]), fmaxf(lds[3][2][d], lds[3][3][d]));
    float ac = lds[4][0][d] + lds[4][1][d] + lds[4][2][d] + lds[4][3][d];
    const int h = d >> 6;
    float denom = ldsl[0][h] + ldsl[1][h] + ldsl[2][h] + ldsl[3][h];
    float att = (denom > 0.f) ? ac / denom : 0.f;

    float* mrow = merged + (size_t)b * 1024;
    mrow[256 + d] = att;
    mrow[512 + d] = mm;
    mrow[768 + d] = ss;
    center  [(size_t)b * DD + d] = cs;
    neighbor[(size_t)b * DD + d] = nm;
}

// ---------------------------------------------------------------------------
// Generic fp32 tiled GEMM: C[M x ldc] (cols n0..) = A[M x K] @ W[N x K]^T + bias
// 64x64 tile per 256-thread block, BK=32, 4x4 micro-tile per thread.
// ---------------------------------------------------------------------------
__global__ __launch_bounds__(256) void gemm_abt(
    const float* __restrict__ A,
    const float* __restrict__ W,
    const float* __restrict__ bias,
    float* __restrict__ C,
    int K, int ldc)
{
    __shared__ __align__(16) float As[32][68];
    __shared__ __align__(16) float Ws[32][68];

    const int m0 = blockIdx.x * 64;
    const int n0 = blockIdx.y * 64;
    const int t  = threadIdx.x;
    const int tx = t & 15;
    const int ty = t >> 4;
    const int lr = t >> 3;
    const int lk = (t & 7) * 4;

    float acc[4][4] = {};

    for (int k0 = 0; k0 < K; k0 += 32) {
        float4 a0 = *reinterpret_cast<const float4*>(&A[(size_t)(m0 + lr)      * K + k0 + lk]);
        float4 a1 = *reinterpret_cast<const float4*>(&A[(size_t)(m0 + lr + 32) * K + k0 + lk]);
        float4 w0 = *reinterpret_cast<const float4*>(&W[(size_t)(n0 + lr)      * K + k0 + lk]);
        float4 w1 = *reinterpret_cast<const float4*>(&W[(size_t)(n0 + lr + 32) * K + k0 + lk]);

        __syncthreads();
        As[lk+0][lr] = a0.x; As[lk+1][lr] = a0.y; As[lk+2][lr] = a0.z; As[lk+3][lr] = a0.w;
        As[lk+0][lr+32] = a1.x; As[lk+1][lr+32] = a1.y; As[lk+2][lr+32] = a1.z; As[lk+3][lr+32] = a1.w;
        Ws[lk+0][lr] = w0.x; Ws[lk+1][lr] = w0.y; Ws[lk+2][lr] = w0.z; Ws[lk+3][lr] = w0.w;
        Ws[lk+0][lr+32] = w1.x; Ws[lk+1][lr+32] = w1.y; Ws[lk+2][lr+32] = w1.z; Ws[lk+3][lr+32] = w1.w;
        __syncthreads();

        #pragma unroll
        for (int kk = 0; kk < 32; ++kk) {
            float4 av = *reinterpret_cast<const float4*>(&As[kk][ty * 4]);
            float4 wv = *reinterpret_cast<const float4*>(&Ws[kk][tx * 4]);
            float a4[4] = {av.x, av.y, av.z, av.w};
            float w4[4] = {wv.x, wv.y, wv.z, wv.w};
            #pragma unroll
            for (int i = 0; i < 4; ++i)
                #pragma unroll
                for (int j = 0; j < 4; ++j)
                    acc[i][j] = fmaf(a4[i], w4[j], acc[i][j]);
        }
    }

    #pragma unroll
    for (int i = 0; i < 4; ++i) {
        const size_t row = (size_t)(m0 + ty * 4 + i) * ldc + n0;
        #pragma unroll
        for (int j = 0; j < 4; ++j)
            C[row + tx * 4 + j] = acc[i][j] + bias[n0 + tx * 4 + j];
    }
}

// ---------------------------------------------------------------------------
// GRU gate elementwise -> writes rnn_out slice of merged
// ---------------------------------------------------------------------------
__global__ __launch_bounds__(256) void gru_kernel(
    const float* __restrict__ gi,        // (NB, 768)
    const float* __restrict__ gh,        // (NB, 768)
    const float* __restrict__ neighbor,  // (NB, 256)
    float* __restrict__ merged)          // (NB, 1024)
{
    const int b = blockIdx.x;
    const int j = threadIdx.x;
    const float* gib = gi + (size_t)b * 768;
    const float* ghb = gh + (size_t)b * 768;

    float r  = 1.f / (1.f + __expf(-(gib[j]       + ghb[j])));
    float z  = 1.f / (1.f + __expf(-(gib[256 + j] + ghb[256 + j])));
    float ng = tanhf(gib[512 + j] + r * ghb[512 + j]);
    float nb = neighbor[(size_t)b * 256 + j];

    merged[(size_t)b * 1024 + j] = (1.f - z) * ng + z * nb;
}

// ---------------------------------------------------------------------------
extern "C" void kernel_launch(void* const* d_in, const int* in_sizes, int n_in,
                              void* d_out, int out_size, void* d_ws, size_t ws_size,
                              hipStream_t stream) {
    const float* x       = (const float*)d_in[0];
    const int*   seg     = (const int*)  d_in[1];
    const float* att_w   = (const float*)d_in[2];
    const float* w_ih    = (const float*)d_in[3];
    const float* w_hh    = (const float*)d_in[4];
    const float* b_ih    = (const float*)d_in[5];
    const float* b_hh    = (const float*)d_in[6];
    const float* merge_w = (const float*)d_in[7];
    const float* merge_b = (const float*)d_in[8];
    float* out = (float*)d_out;

    float* ws       = (float*)d_ws;
    float* merged   = ws;                              // 4096*1024
    float* center   = merged   + (size_t)NB * 1024;    // 4096*256
    float* neighbor = center   + (size_t)NB * DD;      // 4096*256
    float* gi       = neighbor + (size_t)NB * DD;      // 4096*768
    float* gh       = gi       + (size_t)NB * 768;     // 4096*768

    seg_kernel<<<NB, 256, 0, stream>>>(x, seg, att_w, merged, center, neighbor);

    dim3 g1(NB / 64, 768 / 64);
    gemm_abt<<<g1, 256, 0, stream>>>(center,   w_ih, b_ih, gi, DD, 768);
    gemm_abt<<<g1, 256, 0, stream>>>(neighbor, w_hh, b_hh, gh, DD, 768);

    gru_kernel<<<NB, 256, 0, stream>>>(gi, gh, neighbor, merged);

    dim3 g2(NB / 64, DD / 64);
    gemm_abt<<<g2, 256, 0, stream>>>(merged, merge_w, merge_b, out, 1024, DD);
}

// Round 3
// 235.243 us; speedup vs baseline: 1.6138x; 1.0582x over previous
//
#include <hip/hip_runtime.h>
#include <math.h>

#define NN 500000   // nodes
#define NB 4096     // segments
#define DD 256      // feature dim

// Fast exact-enough gelu: Abramowitz-Stegun 7.1.26 erf (|err| <= 1.5e-7), branchless.
__device__ __forceinline__ float gelu_fast(float x) {
    float z  = fabsf(x) * 0.70710678118654752440f;
    float t  = __builtin_amdgcn_rcpf(fmaf(0.3275911f, z, 1.0f));
    float p  = fmaf(1.061405429f, t, -1.453152027f);
    p = fmaf(p, t, 1.421413741f);
    p = fmaf(p, t, -0.284496736f);
    p = fmaf(p, t, 0.254829592f);
    p = p * t;
    float ez = __expf(-z * z);
    float erfv = copysignf(1.0f - p * ez, x);
    return 0.5f * x * (1.0f + erfv);
}

// ---------------------------------------------------------------------------
// Kernel 1: one block (4 waves) per segment. Wave w handles rows start+4k+w,
// one full row per wave: lane l holds columns 4l..4l+3 (float4).
// 2 rows per iteration, 2-deep prefetch (up to 4 loads in flight / wave).
// Head h = l>>4 (16 lanes per head). Plain-exp segment softmax (logits small).
// ---------------------------------------------------------------------------
__global__ __launch_bounds__(256) void seg_kernel(
    const float* __restrict__ x,
    const int*   __restrict__ seg,
    const float* __restrict__ att_w,
    float* __restrict__ merged,    // (NB, 1024)
    float* __restrict__ center,    // (NB, 256)
    float* __restrict__ neighbor)  // (NB, 256)
{
    const int b   = blockIdx.x;
    const int tid = threadIdx.x;
    const int w   = tid >> 6;     // wave 0..3
    const int l   = tid & 63;     // lane

    // wave-uniform binary search: [start, end) rows of segment b
    int lo = 0, hi = NN;
    while (lo < hi) { int mid = (lo + hi) >> 1; if (seg[mid] < b) lo = mid + 1; else hi = mid; }
    const int start = lo;
    hi = NN;
    while (lo < hi) { int mid = (lo + hi) >> 1; if (seg[mid] <= b) lo = mid + 1; else hi = mid; }
    const int end = lo;

    const float4 aw = *reinterpret_cast<const float4*>(&att_w[4 * l]);

    float c0 = 0.f, c1 = 0.f, c2 = 0.f, c3 = 0.f;            // segsum(gelu)
    float n0 = -INFINITY, n1 = -INFINITY, n2 = -INFINITY, n3 = -INFINITY;  // segmax(gelu)
    float s0 = 0.f, s1 = 0.f, s2 = 0.f, s3 = 0.f;            // segsum(x)
    float m0 = -INFINITY, m1 = -INFINITY, m2 = -INFINITY, m3 = -INFINITY;  // segmax(x)
    float a0 = 0.f, a1 = 0.f, a2 = 0.f, a3 = 0.f;            // sum e*x
    float lsum = 0.f;                                         // sum e (per head)

    auto process = [&](const float4& v) {
        float g0 = gelu_fast(v.x), g1 = gelu_fast(v.y), g2 = gelu_fast(v.z), g3 = gelu_fast(v.w);
        c0 += g0; c1 += g1; c2 += g2; c3 += g3;
        n0 = fmaxf(n0, g0); n1 = fmaxf(n1, g1); n2 = fmaxf(n2, g2); n3 = fmaxf(n3, g3);
        s0 += v.x; s1 += v.y; s2 += v.z; s3 += v.w;
        m0 = fmaxf(m0, v.x); m1 = fmaxf(m1, v.y); m2 = fmaxf(m2, v.z); m3 = fmaxf(m3, v.w);
        float t = fmaf(v.x, aw.x, fmaf(v.y, aw.y, fmaf(v.z, aw.z, v.w * aw.w)));
        t += __shfl_xor(t, 1, 64);
        t += __shfl_xor(t, 2, 64);
        t += __shfl_xor(t, 4, 64);
        t += __shfl_xor(t, 8, 64);
        float alpha = fmaxf(t, 0.2f * t);   // leaky_relu(0.2), branchless
        float e = __expf(alpha);
        lsum += e;
        a0 = fmaf(e, v.x, a0); a1 = fmaf(e, v.y, a1); a2 = fmaf(e, v.z, a2); a3 = fmaf(e, v.w, a3);
    };

    const float* __restrict__ xl = x + 4 * l;
    int i0 = start + w, i1 = i0 + 4;
    float4 v0h, v1h;
    if (i0 < end) v0h = *reinterpret_cast<const float4*>(&xl[(size_t)i0 * DD]);
    if (i1 < end) v1h = *reinterpret_cast<const float4*>(&xl[(size_t)i1 * DD]);
    while (i0 < end) {
        const int j0 = i0 + 8, j1 = i0 + 12;
        float4 w0h, w1h;
        if (j0 < end) w0h = *reinterpret_cast<const float4*>(&xl[(size_t)j0 * DD]);
        if (j1 < end) w1h = *reinterpret_cast<const float4*>(&xl[(size_t)j1 * DD]);
        process(v0h);
        if (i1 < end) process(v1h);
        v0h = w0h; v1h = w1h;
        i0 = j0; i1 = j1;
    }

    // ---- cross-wave combine ----
    __shared__ float lds[5][4][256];   // c, n, s, m, a  (20 KB)
    __shared__ float ldsl[4][4];       // per-wave per-head denom partials
    const int c = 4 * l;
    lds[0][w][c+0] = c0; lds[0][w][c+1] = c1; lds[0][w][c+2] = c2; lds[0][w][c+3] = c3;
    lds[1][w][c+0] = n0; lds[1][w][c+1] = n1; lds[1][w][c+2] = n2; lds[1][w][c+3] = n3;
    lds[2][w][c+0] = s0; lds[2][w][c+1] = s1; lds[2][w][c+2] = s2; lds[2][w][c+3] = s3;
    lds[3][w][c+0] = m0; lds[3][w][c+1] = m1; lds[3][w][c+2] = m2; lds[3][w][c+3] = m3;
    lds[4][w][c+0] = a0; lds[4][w][c+1] = a1; lds[4][w][c+2] = a2; lds[4][w][c+3] = a3;
    if ((l & 15) == 0) ldsl[w][l >> 4] = lsum;
    __syncthreads();

    const int d = tid;   // output column
    float cs = lds[0][0][d] + lds[0][1][d] + lds[0][2][d] + lds[0][3][d];
    float nm = fmaxf(fmaxf(lds[1][0][d], lds[1][1][d]), fmaxf(lds[1][2][d], lds[1][3][d]));
    float ss = lds[2][0][d] + lds[2][1][d] + lds[2][2][d] + lds[2][3][d];
    float mm = fmaxf(fmaxf(lds[3][0][d], lds[3][1][d]), fmaxf(lds[3][2][d], lds[3][3][d]));
    float ac = lds[4][0][d] + lds[4][1][d] + lds[4][2][d] + lds[4][3][d];
    const int h = d >> 6;
    float denom = ldsl[0][h] + ldsl[1][h] + ldsl[2][h] + ldsl[3][h];
    float att = (denom > 0.f) ? ac / denom : 0.f;

    float* mrow = merged + (size_t)b * 1024;
    mrow[256 + d] = att;
    mrow[512 + d] = mm;
    mrow[768 + d] = ss;
    center  [(size_t)b * DD + d] = cs;
    neighbor[(size_t)b * DD + d] = nm;
}

// ---------------------------------------------------------------------------
// fp32 tiled GEMM: C[M x ldc] = A[M x K] @ W[N x K]^T + bias
// 64x64 tile / 256 threads, BK=32, 4x4 micro-tile. gridDim.z picks (A,W,b,C).
// ---------------------------------------------------------------------------
__device__ __forceinline__ void gemm_body(
    const float* __restrict__ A, const float* __restrict__ W,
    const float* __restrict__ bias, float* __restrict__ C, int K, int ldc)
{
    __shared__ __align__(16) float As[32][68];
    __shared__ __align__(16) float Ws[32][68];

    const int m0 = blockIdx.x * 64;
    const int n0 = blockIdx.y * 64;
    const int t  = threadIdx.x;
    const int tx = t & 15;
    const int ty = t >> 4;
    const int lr = t >> 3;
    const int lk = (t & 7) * 4;

    float acc[4][4] = {};

    for (int k0 = 0; k0 < K; k0 += 32) {
        float4 a0 = *reinterpret_cast<const float4*>(&A[(size_t)(m0 + lr)      * K + k0 + lk]);
        float4 a1 = *reinterpret_cast<const float4*>(&A[(size_t)(m0 + lr + 32) * K + k0 + lk]);
        float4 w0 = *reinterpret_cast<const float4*>(&W[(size_t)(n0 + lr)      * K + k0 + lk]);
        float4 w1 = *reinterpret_cast<const float4*>(&W[(size_t)(n0 + lr + 32) * K + k0 + lk]);

        __syncthreads();
        As[lk+0][lr] = a0.x; As[lk+1][lr] = a0.y; As[lk+2][lr] = a0.z; As[lk+3][lr] = a0.w;
        As[lk+0][lr+32] = a1.x; As[lk+1][lr+32] = a1.y; As[lk+2][lr+32] = a1.z; As[lk+3][lr+32] = a1.w;
        Ws[lk+0][lr] = w0.x; Ws[lk+1][lr] = w0.y; Ws[lk+2][lr] = w0.z; Ws[lk+3][lr] = w0.w;
        Ws[lk+0][lr+32] = w1.x; Ws[lk+1][lr+32] = w1.y; Ws[lk+2][lr+32] = w1.z; Ws[lk+3][lr+32] = w1.w;
        __syncthreads();

        #pragma unroll
        for (int kk = 0; kk < 32; ++kk) {
            float4 av = *reinterpret_cast<const float4*>(&As[kk][ty * 4]);
            float4 wv = *reinterpret_cast<const float4*>(&Ws[kk][tx * 4]);
            float a4[4] = {av.x, av.y, av.z, av.w};
            float w4[4] = {wv.x, wv.y, wv.z, wv.w};
            #pragma unroll
            for (int i = 0; i < 4; ++i)
                #pragma unroll
                for (int j = 0; j < 4; ++j)
                    acc[i][j] = fmaf(a4[i], w4[j], acc[i][j]);
        }
    }

    #pragma unroll
    for (int i = 0; i < 4; ++i) {
        const size_t row = (size_t)(m0 + ty * 4 + i) * ldc + n0;
        #pragma unroll
        for (int j = 0; j < 4; ++j)
            C[row + tx * 4 + j] = acc[i][j] + bias[n0 + tx * 4 + j];
    }
}

__global__ __launch_bounds__(256) void gemm_abt(
    const float* __restrict__ A, const float* __restrict__ W,
    const float* __restrict__ bias, float* __restrict__ C, int K, int ldc)
{
    gemm_body(A, W, bias, C, K, ldc);
}

__global__ __launch_bounds__(256) void gemm_abt2(
    const float* __restrict__ A0, const float* __restrict__ A1,
    const float* __restrict__ W0, const float* __restrict__ W1,
    const float* __restrict__ b0, const float* __restrict__ b1,
    float* __restrict__ C0, float* __restrict__ C1, int K, int ldc)
{
    if (blockIdx.z == 0) gemm_body(A0, W0, b0, C0, K, ldc);
    else                 gemm_body(A1, W1, b1, C1, K, ldc);
}

// ---------------------------------------------------------------------------
// GRU gate elementwise -> writes rnn_out slice of merged
// ---------------------------------------------------------------------------
__global__ __launch_bounds__(256) void gru_kernel(
    const float* __restrict__ gi,        // (NB, 768)
    const float* __restrict__ gh,        // (NB, 768)
    const float* __restrict__ neighbor,  // (NB, 256)
    float* __restrict__ merged)          // (NB, 1024)
{
    const int b = blockIdx.x;
    const int j = threadIdx.x;
    const float* gib = gi + (size_t)b * 768;
    const float* ghb = gh + (size_t)b * 768;

    float r  = 1.f / (1.f + __expf(-(gib[j]       + ghb[j])));
    float z  = 1.f / (1.f + __expf(-(gib[256 + j] + ghb[256 + j])));
    float ng = tanhf(gib[512 + j] + r * ghb[512 + j]);
    float nb = neighbor[(size_t)b * 256 + j];

    merged[(size_t)b * 1024 + j] = (1.f - z) * ng + z * nb;
}

// ---------------------------------------------------------------------------
extern "C" void kernel_launch(void* const* d_in, const int* in_sizes, int n_in,
                              void* d_out, int out_size, void* d_ws, size_t ws_size,
                              hipStream_t stream) {
    const float* x       = (const float*)d_in[0];
    const int*   seg     = (const int*)  d_in[1];
    const float* att_w   = (const float*)d_in[2];
    const float* w_ih    = (const float*)d_in[3];
    const float* w_hh    = (const float*)d_in[4];
    const float* b_ih    = (const float*)d_in[5];
    const float* b_hh    = (const float*)d_in[6];
    const float* merge_w = (const float*)d_in[7];
    const float* merge_b = (const float*)d_in[8];
    float* out = (float*)d_out;

    float* ws       = (float*)d_ws;
    float* merged   = ws;                              // 4096*1024
    float* center   = merged   + (size_t)NB * 1024;    // 4096*256
    float* neighbor = center   + (size_t)NB * DD;      // 4096*256
    float* gi       = neighbor + (size_t)NB * DD;      // 4096*768
    float* gh       = gi       + (size_t)NB * 768;     // 4096*768

    seg_kernel<<<NB, 256, 0, stream>>>(x, seg, att_w, merged, center, neighbor);

    dim3 g1(NB / 64, 768 / 64, 2);
    gemm_abt2<<<g1, 256, 0, stream>>>(center, neighbor, w_ih, w_hh, b_ih, b_hh, gi, gh, DD, 768);

    gru_kernel<<<NB, 256, 0, stream>>>(gi, gh, neighbor, merged);

    dim3 g2(NB / 64, DD / 64);
    gemm_abt<<<g2, 256, 0, stream>>>(merged, merge_w, merge_b, out, 1024, DD);
}

// Round 4
// 187.388 us; speedup vs baseline: 2.0260x; 1.2554x over previous
//
#include <hip/hip_runtime.h>
#include <math.h>
#include <stdint.h>

#define NN 500000   // nodes
#define NB 4096     // segments
#define DD 256      // feature dim

typedef short  short8  __attribute__((ext_vector_type(8)));
typedef float  floatx4 __attribute__((ext_vector_type(4)));

// fp32 -> bf16 round-to-nearest-even
__device__ __forceinline__ short f2bf(float f) {
    uint32_t u = __float_as_uint(f);
    u += 0x7fffu + ((u >> 16) & 1u);
    return (short)(u >> 16);
}

// Fast exact-enough gelu: Abramowitz-Stegun 7.1.26 erf (|err| <= 1.5e-7), branchless.
__device__ __forceinline__ float gelu_fast(float x) {
    float z  = fabsf(x) * 0.70710678118654752440f;
    float t  = __builtin_amdgcn_rcpf(fmaf(0.3275911f, z, 1.0f));
    float p  = fmaf(1.061405429f, t, -1.453152027f);
    p = fmaf(p, t, 1.421413741f);
    p = fmaf(p, t, -0.284496736f);
    p = fmaf(p, t, 0.254829592f);
    p = p * t;
    float ez = __expf(-z * z);
    float erfv = copysignf(1.0f - p * ez, x);
    return 0.5f * x * (1.0f + erfv);
}

// ---------------------------------------------------------------------------
// Kernel 1: one block (4 waves) per segment. Wave w handles a CONTIGUOUS chunk
// of the segment's rows; lane l holds columns 4l..4l+3 (float4 = full row/wave).
// 2 rows/iter, 4 rows resident, clamped prefetch (no guards in steady state).
// Head h = l>>4 (16 lanes per head). Plain-exp segment softmax (logits small).
// ---------------------------------------------------------------------------
__global__ __launch_bounds__(256) void seg_kernel(
    const float* __restrict__ x,
    const int*   __restrict__ seg,
    const float* __restrict__ att_w,
    float* __restrict__ merged,    // (NB, 1024)
    float* __restrict__ center,    // (NB, 256)
    float* __restrict__ neighbor)  // (NB, 256)
{
    const int b   = blockIdx.x;
    const int tid = threadIdx.x;
    const int w   = tid >> 6;     // wave 0..3
    const int l   = tid & 63;     // lane

    // wave-uniform binary search: [start, end) rows of segment b
    int lo = 0, hi = NN;
    while (lo < hi) { int mid = (lo + hi) >> 1; if (seg[mid] < b) lo = mid + 1; else hi = mid; }
    const int start = lo;
    hi = NN;
    while (lo < hi) { int mid = (lo + hi) >> 1; if (seg[mid] <= b) lo = mid + 1; else hi = mid; }
    const int end = lo;

    // contiguous chunk for this wave
    const int cnt = end - start;
    const int q = cnt >> 2, r = cnt & 3;
    const int my_start = start + w * q + (w < r ? w : r);
    const int my_cnt   = q + (w < r ? 1 : 0);

    const float4 aw = *reinterpret_cast<const float4*>(&att_w[4 * l]);

    float c0 = 0.f, c1 = 0.f, c2 = 0.f, c3 = 0.f;            // segsum(gelu)
    float n0 = -INFINITY, n1 = -INFINITY, n2 = -INFINITY, n3 = -INFINITY;  // segmax(gelu)
    float s0 = 0.f, s1 = 0.f, s2 = 0.f, s3 = 0.f;            // segsum(x)
    float m0 = -INFINITY, m1 = -INFINITY, m2 = -INFINITY, m3 = -INFINITY;  // segmax(x)
    float a0 = 0.f, a1 = 0.f, a2 = 0.f, a3 = 0.f;            // sum e*x
    float lsum = 0.f;                                         // sum e (per head)

    auto process = [&](const float4& v) {
        float g0 = gelu_fast(v.x), g1 = gelu_fast(v.y), g2 = gelu_fast(v.z), g3 = gelu_fast(v.w);
        c0 += g0; c1 += g1; c2 += g2; c3 += g3;
        n0 = fmaxf(n0, g0); n1 = fmaxf(n1, g1); n2 = fmaxf(n2, g2); n3 = fmaxf(n3, g3);
        s0 += v.x; s1 += v.y; s2 += v.z; s3 += v.w;
        m0 = fmaxf(m0, v.x); m1 = fmaxf(m1, v.y); m2 = fmaxf(m2, v.z); m3 = fmaxf(m3, v.w);
        float t = fmaf(v.x, aw.x, fmaf(v.y, aw.y, fmaf(v.z, aw.z, v.w * aw.w)));
        t += __shfl_xor(t, 1, 64);
        t += __shfl_xor(t, 2, 64);
        t += __shfl_xor(t, 4, 64);
        t += __shfl_xor(t, 8, 64);
        float alpha = fmaxf(t, 0.2f * t);   // leaky_relu(0.2), branchless
        float e = __expf(alpha);
        lsum += e;
        a0 = fmaf(e, v.x, a0); a1 = fmaf(e, v.y, a1); a2 = fmaf(e, v.z, a2); a3 = fmaf(e, v.w, a3);
    };

    const float* __restrict__ xl = x + 4 * l;
    auto LD = [&](int row) -> float4 {
        int rc = row < (NN - 1) ? row : (NN - 1);   // clamp: over-reads discarded
        return *reinterpret_cast<const float4*>(&xl[(size_t)rc * DD]);
    };

    // 4 rows resident, 2 processed per iteration, prefetch 2 ahead
    float4 q0 = LD(my_start), q1 = LD(my_start + 1),
           q2 = LD(my_start + 2), q3 = LD(my_start + 3);
    int ip = my_start + 4;
    int rem = my_cnt;
    while (rem >= 2) {
        float4 f0 = LD(ip), f1 = LD(ip + 1);
        process(q0); process(q1);
        q0 = q2; q1 = q3; q2 = f0; q3 = f1;
        ip += 2; rem -= 2;
    }
    if (rem) process(q0);

    // ---- cross-wave combine ----
    __shared__ float lds[5][4][256];   // c, n, s, m, a  (20 KB)
    __shared__ float ldsl[4][4];       // per-wave per-head denom partials
    const int c = 4 * l;
    lds[0][w][c+0] = c0; lds[0][w][c+1] = c1; lds[0][w][c+2] = c2; lds[0][w][c+3] = c3;
    lds[1][w][c+0] = n0; lds[1][w][c+1] = n1; lds[1][w][c+2] = n2; lds[1][w][c+3] = n3;
    lds[2][w][c+0] = s0; lds[2][w][c+1] = s1; lds[2][w][c+2] = s2; lds[2][w][c+3] = s3;
    lds[3][w][c+0] = m0; lds[3][w][c+1] = m1; lds[3][w][c+2] = m2; lds[3][w][c+3] = m3;
    lds[4][w][c+0] = a0; lds[4][w][c+1] = a1; lds[4][w][c+2] = a2; lds[4][w][c+3] = a3;
    if ((l & 15) == 0) ldsl[w][l >> 4] = lsum;
    __syncthreads();

    const int d = tid;   // output column
    float cs = lds[0][0][d] + lds[0][1][d] + lds[0][2][d] + lds[0][3][d];
    float nm = fmaxf(fmaxf(lds[1][0][d], lds[1][1][d]), fmaxf(lds[1][2][d], lds[1][3][d]));
    float ss = lds[2][0][d] + lds[2][1][d] + lds[2][2][d] + lds[2][3][d];
    float mm = fmaxf(fmaxf(lds[3][0][d], lds[3][1][d]), fmaxf(lds[3][2][d], lds[3][3][d]));
    float ac = lds[4][0][d] + lds[4][1][d] + lds[4][2][d] + lds[4][3][d];
    const int h = d >> 6;
    float denom = ldsl[0][h] + ldsl[1][h] + ldsl[2][h] + ldsl[3][h];
    float att = (denom > 0.f) ? ac / denom : 0.f;

    float* mrow = merged + (size_t)b * 1024;
    mrow[256 + d] = att;
    mrow[512 + d] = mm;
    mrow[768 + d] = ss;
    center  [(size_t)b * DD + d] = cs;
    neighbor[(size_t)b * DD + d] = nm;
}

// ---------------------------------------------------------------------------
// bf16 MFMA GEMM: C[M x ldc] = A[M x K] @ W[N x K]^T + bias.  A, W fp32 in
// global; converted to bf16 during LDS staging. fp32 accumulation.
// 64x64 tile / 256 threads (4 waves, 2x2), BK=32, 2x2 16x16x32 frags per wave.
// M, N multiples of 64; K multiple of 32.
// LDS row stride 40 shorts (80 B) -> 2-way bank aliasing on b128 reads (free).
// ---------------------------------------------------------------------------
__device__ __forceinline__ void mfma_gemm_body(
    const float* __restrict__ A, const float* __restrict__ W,
    const float* __restrict__ bias, float* __restrict__ C,
    int K, int ldc)
{
    __shared__ short As[64 * 40];
    __shared__ short Bs[64 * 40];

    const int t   = threadIdx.x;
    const int w   = t >> 6, l = t & 63;
    const int wm  = w >> 1, wn = w & 1;
    const int m0  = blockIdx.x * 64, n0 = blockIdx.y * 64;
    const int lr  = t >> 2;          // staging row 0..63
    const int lc  = (t & 3) * 8;     // staging k-offset (8 elems = 32 B fp32)
    const int l15 = l & 15, lq = l >> 4;

    floatx4 acc[2][2] = {};

    for (int k0 = 0; k0 < K; k0 += 32) {
        const float* ar = &A[(size_t)(m0 + lr) * K + k0 + lc];
        const float* wr = &W[(size_t)(n0 + lr) * K + k0 + lc];
        float4 av0 = *(const float4*)(ar);
        float4 av1 = *(const float4*)(ar + 4);
        float4 wv0 = *(const float4*)(wr);
        float4 wv1 = *(const float4*)(wr + 4);

        __syncthreads();   // previous iteration's fragment reads done
        short8 a8 = { f2bf(av0.x), f2bf(av0.y), f2bf(av0.z), f2bf(av0.w),
                      f2bf(av1.x), f2bf(av1.y), f2bf(av1.z), f2bf(av1.w) };
        short8 w8 = { f2bf(wv0.x), f2bf(wv0.y), f2bf(wv0.z), f2bf(wv0.w),
                      f2bf(wv1.x), f2bf(wv1.y), f2bf(wv1.z), f2bf(wv1.w) };
        *(short8*)&As[lr * 40 + lc] = a8;
        *(short8*)&Bs[lr * 40 + lc] = w8;
        __syncthreads();

        // fragments: lane supplies row/col = l&15, k = (l>>4)*8 + e.
        // (Any consistent within-tile k-permutation cancels between A and B.)
        short8 af0 = *(short8*)&As[(wm * 32 +      l15) * 40 + lq * 8];
        short8 af1 = *(short8*)&As[(wm * 32 + 16 + l15) * 40 + lq * 8];
        short8 bf0 = *(short8*)&Bs[(wn * 32 +      l15) * 40 + lq * 8];
        short8 bf1 = *(short8*)&Bs[(wn * 32 + 16 + l15) * 40 + lq * 8];

        acc[0][0] = __builtin_amdgcn_mfma_f32_16x16x32_bf16(af0, bf0, acc[0][0], 0, 0, 0);
        acc[0][1] = __builtin_amdgcn_mfma_f32_16x16x32_bf16(af0, bf1, acc[0][1], 0, 0, 0);
        acc[1][0] = __builtin_amdgcn_mfma_f32_16x16x32_bf16(af1, bf0, acc[1][0], 0, 0, 0);
        acc[1][1] = __builtin_amdgcn_mfma_f32_16x16x32_bf16(af1, bf1, acc[1][1], 0, 0, 0);
    }

    // epilogue: C/D layout col = lane&15, row = (lane>>4)*4 + reg  [m89-verified]
    #pragma unroll
    for (int i = 0; i < 2; ++i) {
        #pragma unroll
        for (int j = 0; j < 2; ++j) {
            const int col = n0 + wn * 32 + 16 * j + l15;
            const float bv = bias[col];
            #pragma unroll
            for (int qq = 0; qq < 4; ++qq) {
                const int row = m0 + wm * 32 + 16 * i + lq * 4 + qq;
                C[(size_t)row * ldc + col] = acc[i][j][qq] + bv;
            }
        }
    }
}

__global__ __launch_bounds__(256) void gemm_bf16(
    const float* __restrict__ A, const float* __restrict__ W,
    const float* __restrict__ bias, float* __restrict__ C, int K, int ldc)
{
    mfma_gemm_body(A, W, bias, C, K, ldc);
}

__global__ __launch_bounds__(256) void gemm_bf16_2(
    const float* __restrict__ A0, const float* __restrict__ A1,
    const float* __restrict__ W0, const float* __restrict__ W1,
    const float* __restrict__ b0, const float* __restrict__ b1,
    float* __restrict__ C0, float* __restrict__ C1, int K, int ldc)
{
    if (blockIdx.z == 0) mfma_gemm_body(A0, W0, b0, C0, K, ldc);
    else                 mfma_gemm_body(A1, W1, b1, C1, K, ldc);
}

// ---------------------------------------------------------------------------
// GRU gate elementwise -> writes rnn_out slice of merged
// ---------------------------------------------------------------------------
__global__ __launch_bounds__(256) void gru_kernel(
    const float* __restrict__ gi,        // (NB, 768)
    const float* __restrict__ gh,        // (NB, 768)
    const float* __restrict__ neighbor,  // (NB, 256)
    float* __restrict__ merged)          // (NB, 1024)
{
    const int b = blockIdx.x;
    const int j = threadIdx.x;
    const float* gib = gi + (size_t)b * 768;
    const float* ghb = gh + (size_t)b * 768;

    float r  = 1.f / (1.f + __expf(-(gib[j]       + ghb[j])));
    float z  = 1.f / (1.f + __expf(-(gib[256 + j] + ghb[256 + j])));
    float ng = tanhf(gib[512 + j] + r * ghb[512 + j]);
    float nb = neighbor[(size_t)b * 256 + j];

    merged[(size_t)b * 1024 + j] = (1.f - z) * ng + z * nb;
}

// ---------------------------------------------------------------------------
extern "C" void kernel_launch(void* const* d_in, const int* in_sizes, int n_in,
                              void* d_out, int out_size, void* d_ws, size_t ws_size,
                              hipStream_t stream) {
    const float* x       = (const float*)d_in[0];
    const int*   seg     = (const int*)  d_in[1];
    const float* att_w   = (const float*)d_in[2];
    const float* w_ih    = (const float*)d_in[3];
    const float* w_hh    = (const float*)d_in[4];
    const float* b_ih    = (const float*)d_in[5];
    const float* b_hh    = (const float*)d_in[6];
    const float* merge_w = (const float*)d_in[7];
    const float* merge_b = (const float*)d_in[8];
    float* out = (float*)d_out;

    float* ws       = (float*)d_ws;
    float* merged   = ws;                              // 4096*1024
    float* center   = merged   + (size_t)NB * 1024;    // 4096*256
    float* neighbor = center   + (size_t)NB * DD;      // 4096*256
    float* gi       = neighbor + (size_t)NB * DD;      // 4096*768
    float* gh       = gi       + (size_t)NB * 768;     // 4096*768

    seg_kernel<<<NB, 256, 0, stream>>>(x, seg, att_w, merged, center, neighbor);

    dim3 g1(NB / 64, 768 / 64, 2);
    gemm_bf16_2<<<g1, 256, 0, stream>>>(center, neighbor, w_ih, w_hh, b_ih, b_hh, gi, gh, DD, 768);

    gru_kernel<<<NB, 256, 0, stream>>>(gi, gh, neighbor, merged);

    dim3 g2(NB / 64, DD / 64);
    gemm_bf16<<<g2, 256, 0, stream>>>(merged, merge_w, merge_b, out, 1024, DD);
}